// Round 3
// baseline (120.121 us; speedup 1.0000x reference)
//
#include <hip/hip_runtime.h>

// DCT2D_Layer: 8x8 block DCT-II (norm=None) + zigzag reorder.
// img [16,3,512,512] f32 -> out [16, 3*64, 64, 64] f32
// v3: 2 horizontally-adjacent blocks per thread. Loads: 4x float4 = 64B
//     contiguous per row per thread. Stores: float2 per plane (wave-store =
//     512B contiguous, halved store instruction count vs v2).

// 2*cos(m*pi/16)
#define K1 1.9615705608064609f
#define K2 1.8477590650225735f
#define K3 1.6629392246050905f
#define K4 1.4142135623730951f
#define K5 1.1111404660392044f
#define K6 0.7653668647301796f
#define K7 0.3901806440322565f

// Unnormalized DCT-II, factor 2: y[k] = 2*sum_n x[n] cos(pi*(2n+1)k/16)
#define DCT8(x0,x1,x2,x3,x4,x5,x6,x7, y0,y1,y2,y3,y4,y5,y6,y7) do {        \
    float s0=(x0)+(x7), s1=(x1)+(x6), s2=(x2)+(x5), s3=(x3)+(x4);          \
    float d0=(x0)-(x7), d1=(x1)-(x6), d2=(x2)-(x5), d3=(x3)-(x4);          \
    float e0=s0+s3, e1=s1+s2, o0=s0-s3, o1=s1-s2;                          \
    y0 = 2.0f*(e0+e1);                                                     \
    y4 = K4*(e0-e1);                                                       \
    y2 = K2*o0 + K6*o1;                                                    \
    y6 = K6*o0 - K2*o1;                                                    \
    y1 = K1*d0 + K3*d1 + K5*d2 + K7*d3;                                    \
    y3 = K3*d0 - K7*d1 - K1*d2 - K5*d3;                                    \
    y5 = K5*d0 - K1*d1 + K7*d2 + K3*d3;                                    \
    y7 = K7*d0 - K5*d1 + K3*d2 - K1*d3;                                    \
} while (0)

// Row pass r: load 64B (blocks A and B), transform both rows.
#define ROWDCT2(r) do {                                                    \
    const float4 q0 = *reinterpret_cast<const float4*>(src + (r)*512);     \
    const float4 q1 = *reinterpret_cast<const float4*>(src + (r)*512 + 4); \
    const float4 q2 = *reinterpret_cast<const float4*>(src + (r)*512 + 8); \
    const float4 q3 = *reinterpret_cast<const float4*>(src + (r)*512 +12); \
    DCT8(q0.x,q0.y,q0.z,q0.w,q1.x,q1.y,q1.z,q1.w,                          \
         a##r##0,a##r##1,a##r##2,a##r##3,a##r##4,a##r##5,a##r##6,a##r##7); \
    DCT8(q2.x,q2.y,q2.z,q2.w,q3.x,q3.y,q3.z,q3.w,                          \
         b##r##0,b##r##1,b##r##2,b##r##3,b##r##4,b##r##5,b##r##6,b##r##7); \
} while (0)

// Column pass for column v of both blocks; store 8 float2 at zigzag planes.
#define COLSTORE2(v, p0,p1,p2,p3,p4,p5,p6,p7) do {                         \
    float zA0,zA1,zA2,zA3,zA4,zA5,zA6,zA7;                                 \
    float zB0,zB1,zB2,zB3,zB4,zB5,zB6,zB7;                                 \
    DCT8(a0##v,a1##v,a2##v,a3##v,a4##v,a5##v,a6##v,a7##v,                  \
         zA0,zA1,zA2,zA3,zA4,zA5,zA6,zA7);                                 \
    DCT8(b0##v,b1##v,b2##v,b3##v,b4##v,b5##v,b6##v,b7##v,                  \
         zB0,zB1,zB2,zB3,zB4,zB5,zB6,zB7);                                 \
    *reinterpret_cast<float2*>(dst + (size_t)(p0)*4096) = {zA0, zB0};      \
    *reinterpret_cast<float2*>(dst + (size_t)(p1)*4096) = {zA1, zB1};      \
    *reinterpret_cast<float2*>(dst + (size_t)(p2)*4096) = {zA2, zB2};      \
    *reinterpret_cast<float2*>(dst + (size_t)(p3)*4096) = {zA3, zB3};      \
    *reinterpret_cast<float2*>(dst + (size_t)(p4)*4096) = {zA4, zB4};      \
    *reinterpret_cast<float2*>(dst + (size_t)(p5)*4096) = {zA5, zB5};      \
    *reinterpret_cast<float2*>(dst + (size_t)(p6)*4096) = {zA6, zB6};      \
    *reinterpret_cast<float2*>(dst + (size_t)(p7)*4096) = {zA7, zB7};      \
} while (0)

#define DECL_T(p) \
    float p##00,p##01,p##02,p##03,p##04,p##05,p##06,p##07; \
    float p##10,p##11,p##12,p##13,p##14,p##15,p##16,p##17; \
    float p##20,p##21,p##22,p##23,p##24,p##25,p##26,p##27; \
    float p##30,p##31,p##32,p##33,p##34,p##35,p##36,p##37; \
    float p##40,p##41,p##42,p##43,p##44,p##45,p##46,p##47; \
    float p##50,p##51,p##52,p##53,p##54,p##55,p##56,p##57; \
    float p##60,p##61,p##62,p##63,p##64,p##65,p##66,p##67; \
    float p##70,p##71,p##72,p##73,p##74,p##75,p##76,p##77;

__global__ __launch_bounds__(128, 3) void dct2d_zigzag_kernel(
    const float* __restrict__ img, float* __restrict__ out)
{
    const int tid = blockIdx.x * 128 + threadIdx.x;   // 0 .. 98303
    const int bj2 = tid & 31;         // block-pair col (lane bits 0..4)
    const int bi  = (tid >> 5) & 63;  // block row (lane bit 5 + wg bits)
    const int bc  = tid >> 11;        // b*3 + ch, 0..47

    // Input: img[bc, bi*8 + r, bj2*16 + x]; channel plane = 512*512
    const float* __restrict__ src =
        img + (size_t)bc * 262144 + (size_t)bi * 4096 + (size_t)bj2 * 16;

    // Output: out[bc*64 + k, bi, bj2*2]; plane = 64*64 = 4096
    float* __restrict__ dst =
        out + (size_t)bc * 262144 + (size_t)bi * 64 + (size_t)bj2 * 2;

    DECL_T(a)
    DECL_T(b)

    ROWDCT2(0); ROWDCT2(1); ROWDCT2(2); ROWDCT2(3);
    ROWDCT2(4); ROWDCT2(5); ROWDCT2(6); ROWDCT2(7);

    // Zigzag plane indices per (u,v): INVZZ[u*8+v] as literals.
    COLSTORE2(0,  0,  2,  3,  9, 10, 20, 21, 35);
    COLSTORE2(1,  1,  4,  8, 11, 19, 22, 34, 36);
    COLSTORE2(2,  5,  7, 12, 18, 23, 33, 37, 48);
    COLSTORE2(3,  6, 13, 17, 24, 32, 38, 47, 49);
    COLSTORE2(4, 14, 16, 25, 31, 39, 46, 50, 57);
    COLSTORE2(5, 15, 26, 30, 40, 45, 51, 56, 58);
    COLSTORE2(6, 27, 29, 41, 44, 52, 55, 59, 62);
    COLSTORE2(7, 28, 42, 43, 53, 54, 60, 61, 63);
}

extern "C" void kernel_launch(void* const* d_in, const int* in_sizes, int n_in,
                              void* d_out, int out_size, void* d_ws, size_t ws_size,
                              hipStream_t stream)
{
    const float* img = (const float*)d_in[0];
    float* out = (float*)d_out;
    // 98304 threads; 128/block -> 768 workgroups (3 per CU, balanced)
    dct2d_zigzag_kernel<<<768, 128, 0, stream>>>(img, out);
}

// Round 4
// 94.535 us; speedup vs baseline: 1.2707x; 1.2707x over previous
//
#include <hip/hip_runtime.h>

// DCT2D_Layer: 8x8 block DCT-II (norm=None) + zigzag reorder.
// img [16,3,512,512] f32 -> out [16, 3*64, 64, 64] f32
// v4: v2 structure (1 block/thread, 256-thread wg, 3072 waves = 12/CU) +
//     all 16 float4 loads hoisted before compute (16KB MLP per wave) +
//     nontemporal stores (output never re-read; don't churn L2).

// 2*cos(m*pi/16)
#define K1 1.9615705608064609f
#define K2 1.8477590650225735f
#define K3 1.6629392246050905f
#define K4 1.4142135623730951f
#define K5 1.1111404660392044f
#define K6 0.7653668647301796f
#define K7 0.3901806440322565f

// Unnormalized DCT-II, factor 2: y[k] = 2*sum_n x[n] cos(pi*(2n+1)k/16)
#define DCT8(x0,x1,x2,x3,x4,x5,x6,x7, y0,y1,y2,y3,y4,y5,y6,y7) do {        \
    float s0=(x0)+(x7), s1=(x1)+(x6), s2=(x2)+(x5), s3=(x3)+(x4);          \
    float d0=(x0)-(x7), d1=(x1)-(x6), d2=(x2)-(x5), d3=(x3)-(x4);          \
    float e0=s0+s3, e1=s1+s2, o0=s0-s3, o1=s1-s2;                          \
    y0 = 2.0f*(e0+e1);                                                     \
    y4 = K4*(e0-e1);                                                       \
    y2 = K2*o0 + K6*o1;                                                    \
    y6 = K6*o0 - K2*o1;                                                    \
    y1 = K1*d0 + K3*d1 + K5*d2 + K7*d3;                                    \
    y3 = K3*d0 - K7*d1 - K1*d2 - K5*d3;                                    \
    y5 = K5*d0 - K1*d1 + K7*d2 + K3*d3;                                    \
    y7 = K7*d0 - K5*d1 + K3*d2 - K1*d3;                                    \
} while (0)

// Hoisted load of row r (two float4 = 32B of this thread's 8x8 block row).
#define LOADROW(r)                                                          \
    const float4 L##r##a = *reinterpret_cast<const float4*>(src + (r)*512); \
    const float4 L##r##b = *reinterpret_cast<const float4*>(src + (r)*512 + 4);

// Row-pass DCT on the already-loaded row r.
#define ROWDCT(r)                                                          \
    DCT8(L##r##a.x,L##r##a.y,L##r##a.z,L##r##a.w,                          \
         L##r##b.x,L##r##b.y,L##r##b.z,L##r##b.w,                          \
         t##r##0,t##r##1,t##r##2,t##r##3,t##r##4,t##r##5,t##r##6,t##r##7);

// Column pass for column v; nontemporal-store 8 results at zigzag planes.
#define COLSTORE(v, p0,p1,p2,p3,p4,p5,p6,p7) do {                          \
    float z0,z1,z2,z3,z4,z5,z6,z7;                                         \
    DCT8(t0##v,t1##v,t2##v,t3##v,t4##v,t5##v,t6##v,t7##v,                  \
         z0,z1,z2,z3,z4,z5,z6,z7);                                         \
    __builtin_nontemporal_store(z0, dst + (size_t)(p0)*4096);              \
    __builtin_nontemporal_store(z1, dst + (size_t)(p1)*4096);              \
    __builtin_nontemporal_store(z2, dst + (size_t)(p2)*4096);              \
    __builtin_nontemporal_store(z3, dst + (size_t)(p3)*4096);              \
    __builtin_nontemporal_store(z4, dst + (size_t)(p4)*4096);              \
    __builtin_nontemporal_store(z5, dst + (size_t)(p5)*4096);              \
    __builtin_nontemporal_store(z6, dst + (size_t)(p6)*4096);              \
    __builtin_nontemporal_store(z7, dst + (size_t)(p7)*4096);              \
} while (0)

__global__ __launch_bounds__(256) void dct2d_zigzag_kernel(
    const float* __restrict__ img, float* __restrict__ out)
{
    const int tid = blockIdx.x * 256 + threadIdx.x;   // 0 .. 196607
    const int bj = tid & 63;          // block col (== lane within wave)
    const int bi = (tid >> 6) & 63;   // block row
    const int bc = tid >> 12;         // b*3 + ch, 0..47

    // Input: img[bc, bi*8 + r, bj*8 + x]; channel plane = 512*512 = 262144
    const float* __restrict__ src =
        img + (size_t)bc * 262144 + (size_t)bi * 4096 + (size_t)bj * 8;

    // Output: out[bc*64 + k, bi, bj]; plane = 64*64 = 4096
    float* __restrict__ dst =
        out + (size_t)bc * 262144 + (size_t)bi * 64 + (size_t)bj;

    // Issue all 16 global loads back-to-back: 16KB in flight per wave.
    LOADROW(0) LOADROW(1) LOADROW(2) LOADROW(3)
    LOADROW(4) LOADROW(5) LOADROW(6) LOADROW(7)

    float t00,t01,t02,t03,t04,t05,t06,t07;
    float t10,t11,t12,t13,t14,t15,t16,t17;
    float t20,t21,t22,t23,t24,t25,t26,t27;
    float t30,t31,t32,t33,t34,t35,t36,t37;
    float t40,t41,t42,t43,t44,t45,t46,t47;
    float t50,t51,t52,t53,t54,t55,t56,t57;
    float t60,t61,t62,t63,t64,t65,t66,t67;
    float t70,t71,t72,t73,t74,t75,t76,t77;

    ROWDCT(0) ROWDCT(1) ROWDCT(2) ROWDCT(3)
    ROWDCT(4) ROWDCT(5) ROWDCT(6) ROWDCT(7)

    // Zigzag plane indices per (u,v): INVZZ[u*8+v] as literals.
    COLSTORE(0,  0,  2,  3,  9, 10, 20, 21, 35);
    COLSTORE(1,  1,  4,  8, 11, 19, 22, 34, 36);
    COLSTORE(2,  5,  7, 12, 18, 23, 33, 37, 48);
    COLSTORE(3,  6, 13, 17, 24, 32, 38, 47, 49);
    COLSTORE(4, 14, 16, 25, 31, 39, 46, 50, 57);
    COLSTORE(5, 15, 26, 30, 40, 45, 51, 56, 58);
    COLSTORE(6, 27, 29, 41, 44, 52, 55, 59, 62);
    COLSTORE(7, 28, 42, 43, 53, 54, 60, 61, 63);
}

extern "C" void kernel_launch(void* const* d_in, const int* in_sizes, int n_in,
                              void* d_out, int out_size, void* d_ws, size_t ws_size,
                              hipStream_t stream)
{
    const float* img = (const float*)d_in[0];
    float* out = (float*)d_out;
    // 196608 threads; 256/block -> 768 workgroups (3 per CU, 12 waves/CU)
    dct2d_zigzag_kernel<<<768, 256, 0, stream>>>(img, out);
}